// Round 6
// baseline (183.698 us; speedup 1.0000x reference)
//
#include <hip/hip_runtime.h>
#include <math.h>

// ClusterisedSelfAttentionNotLearnable — MFMA, fragment-ordered layouts (R6 = R4 + build fixes).
//   out[n,d] = (1/den[n]) * sum_e enc[n,e] * wbar[n,(d,e)]
//   wbar = exp(scores) @ W'   : GEMM [N,256]x[256,240pad] bf16 16x16x32
// j-space padded to 3 d-blocks of 80 (15 tiles of 16) so d is compile-time per
// tile; pad columns of W' are zero. B (and staged A) live in LDS in exact MFMA
// fragment order: unit u = ((tile*8+ks)*64 + lane) holds the 16B frag lane
// `lane` reads for (tile,ks). Staging = contiguous copy via global_load_lds.

#define NCLUST   256
#define M_BLK    128
#define THREADS  256
#define NTILES   15
#define BG_BYTES (NTILES * 8 * 64 * 16)   // 122880
#define ENC_STRIDE 168                     // bytes/row: 80 bf16 + pad, conflict-free

typedef __attribute__((ext_vector_type(8))) short bfrag_t;   // 8 bf16
typedef __attribute__((ext_vector_type(4))) float cfrag_t;   // 4 f32

static __device__ __forceinline__ unsigned int f2bf_u(float f) {
    unsigned int u = __float_as_uint(f);
    u += 0x7fffu + ((u >> 16) & 1u);     // RNE
    return u >> 16;
}
static __device__ __forceinline__ unsigned int f2bf2(float lo, float hi) {
    return f2bf_u(lo) | (f2bf_u(hi) << 16);
}
static __device__ __forceinline__ float bf2f(unsigned short s) {
    return __uint_as_float(((unsigned int)s) << 16);
}
static __device__ __forceinline__ void glds16(const void* g, void* l) {
    __builtin_amdgcn_global_load_lds(
        (const __attribute__((address_space(1))) unsigned int*)g,
        (__attribute__((address_space(3))) unsigned int*)l, 16, 0, 0);
}

// Build W' in fragment order: unit u -> (tile=u>>9, ks=(u>>6)&7, lane=u&63),
// lane=(q=lane>>4, ln=lane&15); holds W'[j'=tile*16+ln][c=ks*32+q*8 .. +8].
// W'[j'][c] = (e<72) ? W[(c*3+d)*72+e] : 0, with d=j'/80, e=j'-80d.
__global__ void prep_kernel(const float* __restrict__ W, uint4* __restrict__ Bg) {
    const int u = blockIdx.x * 256 + threadIdx.x;
    if (u >= NTILES * 8 * 64) return;
    const int lane = u & 63, ks = (u >> 6) & 7, tile = u >> 9;
    const int ln = lane & 15, q = lane >> 4;
    const int jp = tile * 16 + ln;
    const int d  = jp / 80;
    const int e  = jp - d * 80;
    const int c0 = ks * 32 + q * 8;
    unsigned int w[4] = {0u, 0u, 0u, 0u};
    if (e < 72) {
#pragma unroll
        for (int i = 0; i < 4; ++i) {
            float f0 = W[((c0 + 2 * i)     * 3 + d) * 72 + e];
            float f1 = W[((c0 + 2 * i + 1) * 3 + d) * 72 + e];
            w[i] = f2bf2(f0, f1);
        }
    }
    Bg[u] = make_uint4(w[0], w[1], w[2], w[3]);
}

__global__ __launch_bounds__(THREADS, 4) void rgb_attn_mfma(
    const float* __restrict__ X,
    const float* __restrict__ cent,
    const void* __restrict__ Bg,
    float* __restrict__ out, int N)
{
    __shared__ __align__(16) unsigned char encL[M_BLK * ENC_STRIDE];  // 21504
    __shared__ __align__(16) unsigned char ABbuf[16384];              // A-frags / B-chunk overlay
    __shared__ float denomL[M_BLK * 2];

    const int tid  = threadIdx.x;
    const int lane = tid & 63;
    const int wv   = tid >> 6;
    const int q    = lane >> 4;
    const int ln   = lane & 15;

    const int pt  = tid & 127;
    const int h   = tid >> 7;
    const int gpt = blockIdx.x * M_BLK + pt;
    const int gp  = (gpt < N) ? gpt : (N - 1);

    float x[6];
#pragma unroll
    for (int k = 0; k < 6; ++k) x[k] = X[gp * 6 + k];

    // ---- enc into LDS (bf16, row stride 168 B); zero the e in [72,80) pad ----
    {
        const int row = tid >> 1, half = tid & 1;
        *(uint2*)(encL + row * ENC_STRIDE + 144 + half * 8) = make_uint2(0u, 0u);
    }
#pragma unroll
    for (int k = 0; k < 3; ++k) {
        const int dd = 3 * h + k;
        const float xv = x[dd];
        float s0,c0,s1,c1,s2,c2,s3,c3,s4,c4,s5,c5;
        __sincosf(xv *  1.0f, &s0, &c0);
        __sincosf(xv *  2.0f, &s1, &c1);
        __sincosf(xv *  4.0f, &s2, &c2);
        __sincosf(xv *  8.0f, &s3, &c3);
        __sincosf(xv * 16.0f, &s4, &c4);
        __sincosf(xv * 32.0f, &s5, &c5);
        unsigned char* rp = encL + pt * ENC_STRIDE + dd * 24;
        *(uint2*)(rp +  0) = make_uint2(f2bf2(s0, s1), f2bf2(s2, s3));
        *(uint2*)(rp +  8) = make_uint2(f2bf2(s4, s5), f2bf2(c0, c1));
        *(uint2*)(rp + 16) = make_uint2(f2bf2(c2, c3), f2bf2(c4, c5));
    }

    // ---- attention: 4 phases of 64 clusters; A staged in frag order ----
    bfrag_t afrag[2][8];
    float dpart = 0.0f;
    uint4* AB4 = (uint4*)ABbuf;
#pragma unroll
    for (int p = 0; p < 4; ++p) {
        unsigned int pk[16];
#pragma unroll
        for (int i = 0; i < 16; ++i) {
            const int c0 = p * 64 + h * 32 + 2 * i;
            float sa = fmaf(x[0], cent[c0*3+0], fmaf(x[1], cent[c0*3+1], x[2]*cent[c0*3+2]));
            float sb = fmaf(x[0], cent[c0*3+3], fmaf(x[1], cent[c0*3+4], x[2]*cent[c0*3+5]));
            float ea = __expf(sa), eb_ = __expf(sb);
            dpart += ea + eb_;
            pk[i] = f2bf2(ea, eb_);
        }
        const int bu = ((pt >> 4) * 2 + h) * 64 + (pt & 15);
#pragma unroll
        for (int qq = 0; qq < 4; ++qq)
            AB4[bu + qq * 16] = make_uint4(pk[qq*4+0], pk[qq*4+1], pk[qq*4+2], pk[qq*4+3]);
        if (p == 3) denomL[pt * 2 + h] = dpart;
        __syncthreads();
#pragma unroll
        for (int mt = 0; mt < 2; ++mt)
#pragma unroll
            for (int kw = 0; kw < 2; ++kw)
                afrag[mt][2*p+kw] = *(const bfrag_t*)
                    (ABbuf + (((2*wv+mt)*2 + kw)*64 + lane)*16);
        __syncthreads();
    }

    // ---- main loop: 8 chunks; chunks 0-6 carry 2 tiles, chunk 7 carries 1 ----
    float part[3][2][4] = {};

#define CONSUME_TILE(T, CT) { \
        cfrag_t a0 = {0.f,0.f,0.f,0.f}, a1 = {0.f,0.f,0.f,0.f}; \
        _Pragma("unroll") \
        for (int ks = 0; ks < 8; ++ks) { \
            const bfrag_t b = *(const bfrag_t*) \
                (ABbuf + (((CT)*8 + ks)*64 + lane)*16); \
            a0 = __builtin_amdgcn_mfma_f32_16x16x32_bf16(afrag[0][ks], b, a0, 0,0,0); \
            a1 = __builtin_amdgcn_mfma_f32_16x16x32_bf16(afrag[1][ks], b, a1, 0,0,0); \
        } \
        const int ebx = ((T) % 5) * 16 + ln; \
        _Pragma("unroll") \
        for (int mt = 0; mt < 2; ++mt) \
        _Pragma("unroll") \
        for (int r = 0; r < 4; ++r) { \
            const int pm = (2*wv + mt)*16 + q*4 + r; \
            const unsigned short us = *(const unsigned short*)(encL + pm*ENC_STRIDE + ebx*2); \
            part[(T)/5][mt][r] = fmaf((mt ? a1[r] : a0[r]), bf2f(us), part[(T)/5][mt][r]); \
        } \
    }

#define STAGE_CHUNK(CC, UNITS) { \
        __syncthreads(); \
        _Pragma("unroll") \
        for (int i = 0; i < 256; i += 64) { \
            if (i < (UNITS) / 4) { \
                const int u = wv * ((UNITS) / 4) + i + lane; \
                glds16((const char*)Bg + ((CC)*1024 + u)*16, (char*)ABbuf + u*16); \
            } } \
        __syncthreads(); \
    }

#define DO_CHUNK_FULL(CC) { \
        STAGE_CHUNK(CC, 1024); \
        CONSUME_TILE(2*(CC), 0); \
        CONSUME_TILE(2*(CC)+1, 1); \
    }

    DO_CHUNK_FULL(0) DO_CHUNK_FULL(1) DO_CHUNK_FULL(2) DO_CHUNK_FULL(3)
    DO_CHUNK_FULL(4) DO_CHUNK_FULL(5) DO_CHUNK_FULL(6)
    { STAGE_CHUNK(7, 512); CONSUME_TILE(14, 0); }   // last chunk: single tile

    // ---- reduce across the 16 n-lanes, normalize, write ----
#pragma unroll
    for (int mask = 1; mask <= 8; mask <<= 1)
#pragma unroll
        for (int d = 0; d < 3; ++d)
#pragma unroll
            for (int mt = 0; mt < 2; ++mt)
#pragma unroll
                for (int r = 0; r < 4; ++r)
                    part[d][mt][r] += __shfl_xor(part[d][mt][r], mask, 64);

    if (ln == 0) {
#pragma unroll
        for (int mt = 0; mt < 2; ++mt)
#pragma unroll
            for (int r = 0; r < 4; ++r) {
                const int pm = (2*wv + mt)*16 + q*4 + r;
                const int g  = blockIdx.x * M_BLK + pm;
                if (g < N) {
                    const float inv = 1.0f / (denomL[pm*2] + denomL[pm*2+1]);
                    out[g*3+0] = part[0][mt][r] * inv;
                    out[g*3+1] = part[1][mt][r] * inv;
                    out[g*3+2] = part[2][mt][r] * inv;
                }
            }
    }
}

// ---- fallback (correct, slow) if d_ws too small ----
__global__ __launch_bounds__(256) void rgb_attn_fallback(
    const float* __restrict__ X, const float* __restrict__ W,
    const float* __restrict__ cent, float* __restrict__ out, int N)
{
    const int n = blockIdx.x * 256 + threadIdx.x;
    const bool valid = (n < N);
    float x[6];
#pragma unroll
    for (int k = 0; k < 6; ++k) x[k] = valid ? X[n * 6 + k] : 0.0f;
    float enc[72];
#pragma unroll
    for (int d = 0; d < 6; ++d)
#pragma unroll
        for (int f = 0; f < 6; ++f) {
            float s, c;
            __sincosf(x[d] * (float)(1 << f), &s, &c);
            enc[d*12+f] = s; enc[d*12+6+f] = c;
        }
    float acc0 = 0, acc1 = 0, acc2 = 0, denom = 0;
#pragma unroll 1
    for (int c = 0; c < NCLUST; ++c) {
        float s = fmaf(x[0], cent[c*3], fmaf(x[1], cent[c*3+1], x[2]*cent[c*3+2]));
        float ew = __expf(s);
        const float* w = W + c * 216;
        float d0 = 0, d1 = 0, d2 = 0;
#pragma unroll
        for (int e = 0; e < 72; ++e) {
            float ee = enc[e];
            d0 = fmaf(ee, w[e], d0);
            d1 = fmaf(ee, w[72 + e], d1);
            d2 = fmaf(ee, w[144 + e], d2);
        }
        denom += ew;
        acc0 = fmaf(ew, d0, acc0); acc1 = fmaf(ew, d1, acc1); acc2 = fmaf(ew, d2, acc2);
    }
    if (valid) {
        float inv = 1.0f / denom;
        out[n*3+0] = acc0*inv; out[n*3+1] = acc1*inv; out[n*3+2] = acc2*inv;
    }
}

extern "C" void kernel_launch(void* const* d_in, const int* in_sizes, int n_in,
                              void* d_out, int out_size, void* d_ws, size_t ws_size,
                              hipStream_t stream)
{
    const float* X    = (const float*)d_in[0];   // [N, 6]
    const float* W    = (const float*)d_in[1];   // [768, 72]
    const float* cent = (const float*)d_in[2];   // [256, 3]
    float* out = (float*)d_out;                  // [N, 3]
    const int N = in_sizes[0] / 6;

    if (ws_size >= (size_t)BG_BYTES) {
        uint4* Bg = (uint4*)d_ws;
        prep_kernel<<<(NTILES * 8 * 64 + 255) / 256, 256, 0, stream>>>(W, Bg);
        const int blocks = (N + M_BLK - 1) / M_BLK;
        rgb_attn_mfma<<<blocks, THREADS, 0, stream>>>(X, cent, (const void*)Bg, out, N);
    } else {
        rgb_attn_fallback<<<(N + 255) / 256, 256, 0, stream>>>(X, W, cent, out, N);
    }
}

// Round 7
// 129.765 us; speedup vs baseline: 1.4156x; 1.4156x over previous
//
#include <hip/hip_runtime.h>
#include <math.h>

// ClusterisedSelfAttentionNotLearnable — MFMA, fragment-ordered layouts.
// R7 = R6 with the spill fixed: __launch_bounds__(256,2) (R6's (256,4) capped
// VGPRs at 128 -> compiler spilled afrag/part to scratch -> 524 MB of HBM
// traffic = the whole 137us runtime).
//   out[n,d] = (1/den[n]) * sum_e enc[n,e] * wbar[n,(d,e)]
//   wbar = exp(scores) @ W'   : GEMM [N,256]x[256,240pad] bf16 16x16x32
// j-space padded to 3 d-blocks of 80 (15 tiles of 16) so d is compile-time per
// tile; pad columns of W' are zero. B (and staged A) live in LDS in exact MFMA
// fragment order: unit u = ((tile*8+ks)*64 + lane) holds the 16B frag lane
// `lane` reads for (tile,ks). Staging = contiguous copy via global_load_lds.

#define NCLUST   256
#define M_BLK    128
#define THREADS  256
#define NTILES   15
#define BG_BYTES (NTILES * 8 * 64 * 16)   // 122880
#define ENC_STRIDE 168                     // bytes/row: 80 bf16 + pad, conflict-free

typedef __attribute__((ext_vector_type(8))) short bfrag_t;   // 8 bf16
typedef __attribute__((ext_vector_type(4))) float cfrag_t;   // 4 f32

static __device__ __forceinline__ unsigned int f2bf_u(float f) {
    unsigned int u = __float_as_uint(f);
    u += 0x7fffu + ((u >> 16) & 1u);     // RNE
    return u >> 16;
}
static __device__ __forceinline__ unsigned int f2bf2(float lo, float hi) {
    return f2bf_u(lo) | (f2bf_u(hi) << 16);
}
static __device__ __forceinline__ float bf2f(unsigned short s) {
    return __uint_as_float(((unsigned int)s) << 16);
}
static __device__ __forceinline__ void glds16(const void* g, void* l) {
    __builtin_amdgcn_global_load_lds(
        (const __attribute__((address_space(1))) unsigned int*)g,
        (__attribute__((address_space(3))) unsigned int*)l, 16, 0, 0);
}

// Build W' in fragment order: unit u -> (tile=u>>9, ks=(u>>6)&7, lane=u&63),
// lane=(q=lane>>4, ln=lane&15); holds W'[j'=tile*16+ln][c=ks*32+q*8 .. +8].
// W'[j'][c] = (e<72) ? W[(c*3+d)*72+e] : 0, with d=j'/80, e=j'-80d.
__global__ void prep_kernel(const float* __restrict__ W, uint4* __restrict__ Bg) {
    const int u = blockIdx.x * 256 + threadIdx.x;
    if (u >= NTILES * 8 * 64) return;
    const int lane = u & 63, ks = (u >> 6) & 7, tile = u >> 9;
    const int ln = lane & 15, q = lane >> 4;
    const int jp = tile * 16 + ln;
    const int d  = jp / 80;
    const int e  = jp - d * 80;
    const int c0 = ks * 32 + q * 8;
    unsigned int w[4] = {0u, 0u, 0u, 0u};
    if (e < 72) {
#pragma unroll
        for (int i = 0; i < 4; ++i) {
            float f0 = W[((c0 + 2 * i)     * 3 + d) * 72 + e];
            float f1 = W[((c0 + 2 * i + 1) * 3 + d) * 72 + e];
            w[i] = f2bf2(f0, f1);
        }
    }
    Bg[u] = make_uint4(w[0], w[1], w[2], w[3]);
}

__global__ __launch_bounds__(THREADS, 2) void rgb_attn_mfma(
    const float* __restrict__ X,
    const float* __restrict__ cent,
    const void* __restrict__ Bg,
    float* __restrict__ out, int N)
{
    __shared__ __align__(16) unsigned char encL[M_BLK * ENC_STRIDE];  // 21504
    __shared__ __align__(16) unsigned char ABbuf[16384];              // A-frags / B-chunk overlay
    __shared__ float denomL[M_BLK * 2];

    const int tid  = threadIdx.x;
    const int lane = tid & 63;
    const int wv   = tid >> 6;
    const int q    = lane >> 4;
    const int ln   = lane & 15;

    const int pt  = tid & 127;
    const int h   = tid >> 7;
    const int gpt = blockIdx.x * M_BLK + pt;
    const int gp  = (gpt < N) ? gpt : (N - 1);

    float x[6];
#pragma unroll
    for (int k = 0; k < 6; ++k) x[k] = X[gp * 6 + k];

    // ---- enc into LDS (bf16, row stride 168 B); zero the e in [72,80) pad ----
    {
        const int row = tid >> 1, half = tid & 1;
        *(uint2*)(encL + row * ENC_STRIDE + 144 + half * 8) = make_uint2(0u, 0u);
    }
#pragma unroll
    for (int k = 0; k < 3; ++k) {
        const int dd = 3 * h + k;
        const float xv = x[dd];
        float s0,c0,s1,c1,s2,c2,s3,c3,s4,c4,s5,c5;
        __sincosf(xv *  1.0f, &s0, &c0);
        __sincosf(xv *  2.0f, &s1, &c1);
        __sincosf(xv *  4.0f, &s2, &c2);
        __sincosf(xv *  8.0f, &s3, &c3);
        __sincosf(xv * 16.0f, &s4, &c4);
        __sincosf(xv * 32.0f, &s5, &c5);
        unsigned char* rp = encL + pt * ENC_STRIDE + dd * 24;
        *(uint2*)(rp +  0) = make_uint2(f2bf2(s0, s1), f2bf2(s2, s3));
        *(uint2*)(rp +  8) = make_uint2(f2bf2(s4, s5), f2bf2(c0, c1));
        *(uint2*)(rp + 16) = make_uint2(f2bf2(c2, c3), f2bf2(c4, c5));
    }

    // ---- attention: 4 phases of 64 clusters; A staged in frag order ----
    bfrag_t afrag[2][8];
    float dpart = 0.0f;
    uint4* AB4 = (uint4*)ABbuf;
#pragma unroll
    for (int p = 0; p < 4; ++p) {
        unsigned int pk[16];
#pragma unroll
        for (int i = 0; i < 16; ++i) {
            const int c0 = p * 64 + h * 32 + 2 * i;
            float sa = fmaf(x[0], cent[c0*3+0], fmaf(x[1], cent[c0*3+1], x[2]*cent[c0*3+2]));
            float sb = fmaf(x[0], cent[c0*3+3], fmaf(x[1], cent[c0*3+4], x[2]*cent[c0*3+5]));
            float ea = __expf(sa), eb_ = __expf(sb);
            dpart += ea + eb_;
            pk[i] = f2bf2(ea, eb_);
        }
        const int bu = ((pt >> 4) * 2 + h) * 64 + (pt & 15);
#pragma unroll
        for (int qq = 0; qq < 4; ++qq)
            AB4[bu + qq * 16] = make_uint4(pk[qq*4+0], pk[qq*4+1], pk[qq*4+2], pk[qq*4+3]);
        if (p == 3) denomL[pt * 2 + h] = dpart;
        __syncthreads();
#pragma unroll
        for (int mt = 0; mt < 2; ++mt)
#pragma unroll
            for (int kw = 0; kw < 2; ++kw)
                afrag[mt][2*p+kw] = *(const bfrag_t*)
                    (ABbuf + (((2*wv+mt)*2 + kw)*64 + lane)*16);
        __syncthreads();
    }

    // ---- main loop: 8 chunks; chunks 0-6 carry 2 tiles, chunk 7 carries 1 ----
    float part[3][2][4] = {};

#define CONSUME_TILE(T, CT) { \
        cfrag_t a0 = {0.f,0.f,0.f,0.f}, a1 = {0.f,0.f,0.f,0.f}; \
        _Pragma("unroll") \
        for (int ks = 0; ks < 8; ++ks) { \
            const bfrag_t b = *(const bfrag_t*) \
                (ABbuf + (((CT)*8 + ks)*64 + lane)*16); \
            a0 = __builtin_amdgcn_mfma_f32_16x16x32_bf16(afrag[0][ks], b, a0, 0,0,0); \
            a1 = __builtin_amdgcn_mfma_f32_16x16x32_bf16(afrag[1][ks], b, a1, 0,0,0); \
        } \
        const int ebx = ((T) % 5) * 16 + ln; \
        _Pragma("unroll") \
        for (int mt = 0; mt < 2; ++mt) \
        _Pragma("unroll") \
        for (int r = 0; r < 4; ++r) { \
            const int pm = (2*wv + mt)*16 + q*4 + r; \
            const unsigned short us = *(const unsigned short*)(encL + pm*ENC_STRIDE + ebx*2); \
            part[(T)/5][mt][r] = fmaf((mt ? a1[r] : a0[r]), bf2f(us), part[(T)/5][mt][r]); \
        } \
    }

#define STAGE_CHUNK(CC, UNITS) { \
        __syncthreads(); \
        _Pragma("unroll") \
        for (int i = 0; i < 256; i += 64) { \
            if (i < (UNITS) / 4) { \
                const int u = wv * ((UNITS) / 4) + i + lane; \
                glds16((const char*)Bg + ((CC)*1024 + u)*16, (char*)ABbuf + u*16); \
            } } \
        __syncthreads(); \
    }

#define DO_CHUNK_FULL(CC) { \
        STAGE_CHUNK(CC, 1024); \
        CONSUME_TILE(2*(CC), 0); \
        CONSUME_TILE(2*(CC)+1, 1); \
    }

    DO_CHUNK_FULL(0) DO_CHUNK_FULL(1) DO_CHUNK_FULL(2) DO_CHUNK_FULL(3)
    DO_CHUNK_FULL(4) DO_CHUNK_FULL(5) DO_CHUNK_FULL(6)
    { STAGE_CHUNK(7, 512); CONSUME_TILE(14, 0); }   // last chunk: single tile

    // ---- reduce across the 16 n-lanes, normalize, write ----
#pragma unroll
    for (int mask = 1; mask <= 8; mask <<= 1)
#pragma unroll
        for (int d = 0; d < 3; ++d)
#pragma unroll
            for (int mt = 0; mt < 2; ++mt)
#pragma unroll
                for (int r = 0; r < 4; ++r)
                    part[d][mt][r] += __shfl_xor(part[d][mt][r], mask, 64);

    if (ln == 0) {
#pragma unroll
        for (int mt = 0; mt < 2; ++mt)
#pragma unroll
            for (int r = 0; r < 4; ++r) {
                const int pm = (2*wv + mt)*16 + q*4 + r;
                const int g  = blockIdx.x * M_BLK + pm;
                if (g < N) {
                    const float inv = 1.0f / (denomL[pm*2] + denomL[pm*2+1]);
                    out[g*3+0] = part[0][mt][r] * inv;
                    out[g*3+1] = part[1][mt][r] * inv;
                    out[g*3+2] = part[2][mt][r] * inv;
                }
            }
    }
}

// ---- fallback (correct, slow) if d_ws too small ----
__global__ __launch_bounds__(256) void rgb_attn_fallback(
    const float* __restrict__ X, const float* __restrict__ W,
    const float* __restrict__ cent, float* __restrict__ out, int N)
{
    const int n = blockIdx.x * 256 + threadIdx.x;
    const bool valid = (n < N);
    float x[6];
#pragma unroll
    for (int k = 0; k < 6; ++k) x[k] = valid ? X[n * 6 + k] : 0.0f;
    float enc[72];
#pragma unroll
    for (int d = 0; d < 6; ++d)
#pragma unroll
        for (int f = 0; f < 6; ++f) {
            float s, c;
            __sincosf(x[d] * (float)(1 << f), &s, &c);
            enc[d*12+f] = s; enc[d*12+6+f] = c;
        }
    float acc0 = 0, acc1 = 0, acc2 = 0, denom = 0;
#pragma unroll 1
    for (int c = 0; c < NCLUST; ++c) {
        float s = fmaf(x[0], cent[c*3], fmaf(x[1], cent[c*3+1], x[2]*cent[c*3+2]));
        float ew = __expf(s);
        const float* w = W + c * 216;
        float d0 = 0, d1 = 0, d2 = 0;
#pragma unroll
        for (int e = 0; e < 72; ++e) {
            float ee = enc[e];
            d0 = fmaf(ee, w[e], d0);
            d1 = fmaf(ee, w[72 + e], d1);
            d2 = fmaf(ee, w[144 + e], d2);
        }
        denom += ew;
        acc0 = fmaf(ew, d0, acc0); acc1 = fmaf(ew, d1, acc1); acc2 = fmaf(ew, d2, acc2);
    }
    if (valid) {
        float inv = 1.0f / denom;
        out[n*3+0] = acc0*inv; out[n*3+1] = acc1*inv; out[n*3+2] = acc2*inv;
    }
}

extern "C" void kernel_launch(void* const* d_in, const int* in_sizes, int n_in,
                              void* d_out, int out_size, void* d_ws, size_t ws_size,
                              hipStream_t stream)
{
    const float* X    = (const float*)d_in[0];   // [N, 6]
    const float* W    = (const float*)d_in[1];   // [768, 72]
    const float* cent = (const float*)d_in[2];   // [256, 3]
    float* out = (float*)d_out;                  // [N, 3]
    const int N = in_sizes[0] / 6;

    if (ws_size >= (size_t)BG_BYTES) {
        uint4* Bg = (uint4*)d_ws;
        prep_kernel<<<(NTILES * 8 * 64 + 255) / 256, 256, 0, stream>>>(W, Bg);
        const int blocks = (N + M_BLK - 1) / M_BLK;
        rgb_attn_mfma<<<blocks, THREADS, 0, stream>>>(X, cent, (const void*)Bg, out, N);
    } else {
        rgb_attn_fallback<<<(N + 255) / 256, 256, 0, stream>>>(X, W, cent, out, N);
    }
}